// Round 4
// baseline (71.038 us; speedup 1.0000x reference)
//
#include <hip/hip_runtime.h>
#include <math.h>

#define N 4096
#define G 8               // particles per block (+1 redundant robot slot)
#define SLOTS (G + 1)
#define BLK 512
#define NWAVE (BLK / 64)
#define NJ (N / BLK)      // 8 j-iterations, compile-time -> full unroll

#define EPSF 1e-8f
#define DTF 0.1f
#define PED_SPEEDF 1.4f
#define INV_MASS_DT (0.1f / 60.0f)

// mag = ALPHA * exp((2*R - d)/BETTA) = exp2(C0 - d*C1), ALPHA folded in:
// C1 = 1/(0.71*ln2), C0 = 0.6*C1 + log2(10)
#define C1F 2.0319658f
#define C0F 4.5331072f

// Raw HW transcendentals: one v_rsq_f32 / v_exp_f32 per pair, no ocml fixup.
__device__ __forceinline__ float hw_rsq(float x)  { return __builtin_amdgcn_rsqf(x); }
__device__ __forceinline__ float hw_exp2(float x) { return __builtin_amdgcn_exp2f(x); }

// Fused: pairwise forces + integration + cost in ONE kernel.
// BLK=512, G=8: 512 blocks -> 2 blocks/CU -> 4 waves/SIMD for latency hiding,
// while keeping the 9/8 redundant-robot work ratio.
__global__ __launch_bounds__(BLK, 4) void step_kernel(
    const float* __restrict__ state,    // (N,4): pos.xy, vel.xy
    const float* __restrict__ cost,     // (N,1)
    const float2* __restrict__ goals,   // (N,2)
    const float* __restrict__ rip,      // (2,)
    const float* __restrict__ goal,     // (2,)
    float4* __restrict__ out,           // (N,4)
    float* __restrict__ newcost)        // (N,1)
{
    const int tid = threadIdx.x;
    const int ibase = blockIdx.x * G;

    // block-uniform positions for this block's G particles + robot (particle 0)
    float mex[SLOTS], mey[SLOTS];
#pragma unroll
    for (int g = 0; g < G; ++g) {
        mex[g] = state[(ibase + g) * 4 + 0];
        mey[g] = state[(ibase + g) * 4 + 1];
    }
    mex[G] = state[0];
    mey[G] = state[1];

    float rfx[SLOTS], rfy[SLOTS];
#pragma unroll
    for (int g = 0; g < SLOTS; ++g) { rfx[g] = 0.0f; rfy[g] = 0.0f; }

    const float2* pos2 = (const float2*)state;   // row j's position = pos2[2*j]

    // self-term contributes exactly 0 (diff == 0): no branch needed
#pragma unroll
    for (int jj = 0; jj < NJ; ++jj) {
        float2 o = pos2[2 * (jj * BLK + tid)];
        float ox = o.x, oy = o.y;
#pragma unroll
        for (int g = 0; g < SLOTS; ++g) {
            float dx = mex[g] - ox;
            float dy = mey[g] - oy;
            float d2 = fmaf(dx, dx, fmaf(dy, dy, EPSF));
            float inv = hw_rsq(d2);
            float d = d2 * inv;                        // sqrt(d2+eps)
            float mag = hw_exp2(fmaf(d, -C1F, C0F));   // ALPHA*exp((0.6-d)/0.71)
            float w = mag * inv;                       // mag / d
            rfx[g] = fmaf(w, dx, rfx[g]);
            rfy[g] = fmaf(w, dy, rfy[g]);
        }
    }

    // reduce: wave64 shuffle, then LDS across NWAVE waves
    __shared__ float sredx[NWAVE][SLOTS];
    __shared__ float sredy[NWAVE][SLOTS];
    const int wave = tid >> 6;
    const int lane = tid & 63;
#pragma unroll
    for (int g = 0; g < SLOTS; ++g) {
        float x = rfx[g], y = rfy[g];
#pragma unroll
        for (int off = 32; off > 0; off >>= 1) {
            x += __shfl_down(x, off);
            y += __shfl_down(y, off);
        }
        if (lane == 0) { sredx[wave][g] = x; sredy[wave][g] = y; }
    }
    __syncthreads();

    if (tid < G) {
        const int i = ibase + tid;

        // --- robot (particle 0) update, redundant per block, bitwise identical ---
        float rbfx = 0.0f, rbfy = 0.0f;
        float fx = 0.0f, fy = 0.0f;
#pragma unroll
        for (int w = 0; w < NWAVE; ++w) {
            rbfx += sredx[w][G];  rbfy += sredy[w][G];
            fx   += sredx[w][tid]; fy  += sredy[w][tid];
        }
        float r_px = state[0], r_py = state[1], r_vx = state[2], r_vy = state[3];
        float2 rgl = goals[0];
        float rtgx = rgl.x - r_px, rtgy = rgl.y - r_py;
        float rdg = sqrtf(fmaf(rtgx, rtgx, fmaf(rtgy, rtgy, EPSF)));
        float rs = 1.0f / rdg;                      // robot des_speed = 1.0
        float rFx = rbfx + 2.0f * (rtgx * rs - r_vx);
        float rFy = rbfy + 2.0f * (rtgy * rs - r_vy);
        float rvnx = fmaf(rFx, INV_MASS_DT, r_vx);
        float rvny = fmaf(rFy, INV_MASS_DT, r_vy);
        float rsp = sqrtf(fmaf(rvnx, rvnx, fmaf(rvny, rvny, EPSF)));
        float rsc = fminf(1.0f, PED_SPEEDF / rsp);
        rvnx *= rsc; rvny *= rsc;
        float rpx = fmaf(rvnx, DTF, r_px);          // new robot pose
        float rpy = fmaf(rvny, DTF, r_py);

        // --- this particle's update ---
        float px = state[i * 4 + 0], py = state[i * 4 + 1];
        float vx = state[i * 4 + 2], vy = state[i * 4 + 3];
        float2 gl = goals[i];
        float tgx = gl.x - px, tgy = gl.y - py;
        float distg = sqrtf(fmaf(tgx, tgx, fmaf(tgy, tgy, EPSF)));
        float des = (i == 0) ? 1.0f : PED_SPEEDF;
        float s = des / distg;
        float Fx = fx + 2.0f * (tgx * s - vx);
        float Fy = fy + 2.0f * (tgy * s - vy);
        float vnx = fmaf(Fx, INV_MASS_DT, vx);
        float vny = fmaf(Fy, INV_MASS_DT, vy);
        float sp = sqrtf(fmaf(vnx, vnx, fmaf(vny, vny, EPSF)));
        float scale = fminf(1.0f, PED_SPEEDF / sp);
        vnx *= scale; vny *= scale;
        float pnx = fmaf(vnx, DTF, px);
        float pny = fmaf(vny, DTF, py);
        out[i] = make_float4(pnx, pny, vnx, vny);

        // --- cost, fused ---
        float gx = goal[0], gy = goal[1];
        float ax = rip[0] - gx, ay = rip[1] - gy;
        float bx = rpx - gx, by = rpy - gy;
        float pg = sqrtf(fmaf(ax, ax, fmaf(ay, ay, EPSF)))
                 - sqrtf(fmaf(bx, bx, fmaf(by, by, EPSF)));
        float dx = pnx - rpx, dy = pny - rpy;
        float dr = sqrtf(fmaf(dx, dx, fmaf(dy, dy, EPSF)));
        float e = hw_exp2(dr * (-1.4426950408889634f / 1.5f)); // exp(-dr/1.5)
        newcost[i] = cost[i] + fmaf(5.0f, pg, 2.0f * e);
    }
}

extern "C" void kernel_launch(void* const* d_in, const int* in_sizes, int n_in,
                              void* d_out, int out_size, void* d_ws, size_t ws_size,
                              hipStream_t stream) {
    const float* state = (const float*)d_in[0];
    const float* cost  = (const float*)d_in[1];
    const float* goals = (const float*)d_in[2];
    const float* rip   = (const float*)d_in[3];
    const float* goal  = (const float*)d_in[4];
    float* out = (float*)d_out;

    step_kernel<<<N / G, BLK, 0, stream>>>(
        state, cost, (const float2*)goals, rip, goal,
        (float4*)out, out + 4 * N);
}

// Round 5
// 70.363 us; speedup vs baseline: 1.0096x; 1.0096x over previous
//
#include <hip/hip_runtime.h>
#include <math.h>

#define N 4096
#define G 8               // particles per block (+1 redundant robot slot)
#define SLOTS (G + 1)
#define BLK 256
#define NWAVE (BLK / 64)
#define NJ (N / BLK)      // 16 j-iterations, compile-time -> full unroll

#define EPSF 1e-8f
#define DTF 0.1f
#define PED_SPEEDF 1.4f
#define INV_MASS_DT (0.1f / 60.0f)

// mag = ALPHA * exp((2*R - d)/BETTA) = exp2(C0 - d*C1), ALPHA folded in:
// C1 = 1/(0.71*ln2), C0 = 0.6*C1 + log2(10)
#define C1F 2.0319658f
#define C0F 4.5331072f

typedef float v2f __attribute__((ext_vector_type(2)));

// Raw HW transcendentals: one v_rsq_f32 / v_exp_f32 per pair, no ocml fixup.
__device__ __forceinline__ float hw_rsq(float x)  { return __builtin_amdgcn_rsqf(x); }
__device__ __forceinline__ float hw_exp2(float x) { return __builtin_amdgcn_exp2f(x); }

// Fused: pairwise forces + integration + cost in ONE kernel.
// Inner loop uses float2 ext-vectors to coax v_pk_add_f32 / v_pk_fma_f32
// (CDNA packed fp32): (dx,dy) and the two accumulator FMAs each become one
// packed op -> 34 -> 30 cy per wave64 pair-batch.
__global__ __launch_bounds__(BLK, 2) void step_kernel(
    const float* __restrict__ state,    // (N,4): pos.xy, vel.xy
    const float* __restrict__ cost,     // (N,1)
    const float2* __restrict__ goals,   // (N,2)
    const float* __restrict__ rip,      // (2,)
    const float* __restrict__ goal,     // (2,)
    float4* __restrict__ out,           // (N,4)
    float* __restrict__ newcost)        // (N,1)
{
    const int tid = threadIdx.x;
    const int ibase = blockIdx.x * G;

    // block-uniform positions for this block's G particles + robot (particle 0)
    v2f me[SLOTS];
#pragma unroll
    for (int g = 0; g < G; ++g) {
        me[g].x = state[(ibase + g) * 4 + 0];
        me[g].y = state[(ibase + g) * 4 + 1];
    }
    me[G].x = state[0];
    me[G].y = state[1];

    v2f rf[SLOTS];
#pragma unroll
    for (int g = 0; g < SLOTS; ++g) { rf[g].x = 0.0f; rf[g].y = 0.0f; }

    const float2* pos2 = (const float2*)state;   // row j's position = pos2[2*j]

    // self-term contributes exactly 0 (dxy == 0): no branch needed
#pragma unroll
    for (int jj = 0; jj < NJ; ++jj) {
        float2 oj = pos2[2 * (jj * BLK + tid)];
        v2f o; o.x = oj.x; o.y = oj.y;
#pragma unroll
        for (int g = 0; g < SLOTS; ++g) {
            v2f dxy = me[g] - o;                       // v_pk_add_f32 (neg mod)
            float d2 = fmaf(dxy.x, dxy.x, fmaf(dxy.y, dxy.y, EPSF));
            float inv = hw_rsq(d2);
            float d = d2 * inv;                        // sqrt(d2+eps)
            float mag = hw_exp2(fmaf(d, -C1F, C0F));   // ALPHA*exp((0.6-d)/0.71)
            float w = mag * inv;                       // mag / d
            rf[g] = w * dxy + rf[g];                   // v_pk_fma_f32
        }
    }

    // reduce: wave64 shuffle, then LDS across NWAVE waves
    __shared__ float sredx[NWAVE][SLOTS];
    __shared__ float sredy[NWAVE][SLOTS];
    const int wave = tid >> 6;
    const int lane = tid & 63;
#pragma unroll
    for (int g = 0; g < SLOTS; ++g) {
        float x = rf[g].x, y = rf[g].y;
#pragma unroll
        for (int off = 32; off > 0; off >>= 1) {
            x += __shfl_down(x, off);
            y += __shfl_down(y, off);
        }
        if (lane == 0) { sredx[wave][g] = x; sredy[wave][g] = y; }
    }
    __syncthreads();

    if (tid < G) {
        const int i = ibase + tid;

        // --- robot (particle 0) update, redundant per block, bitwise identical ---
        float rbfx = 0.0f, rbfy = 0.0f;
        float fx = 0.0f, fy = 0.0f;
#pragma unroll
        for (int w = 0; w < NWAVE; ++w) {
            rbfx += sredx[w][G];  rbfy += sredy[w][G];
            fx   += sredx[w][tid]; fy  += sredy[w][tid];
        }
        float r_px = state[0], r_py = state[1], r_vx = state[2], r_vy = state[3];
        float2 rgl = goals[0];
        float rtgx = rgl.x - r_px, rtgy = rgl.y - r_py;
        float rdg = sqrtf(fmaf(rtgx, rtgx, fmaf(rtgy, rtgy, EPSF)));
        float rs = 1.0f / rdg;                      // robot des_speed = 1.0
        float rFx = rbfx + 2.0f * (rtgx * rs - r_vx);
        float rFy = rbfy + 2.0f * (rtgy * rs - r_vy);
        float rvnx = fmaf(rFx, INV_MASS_DT, r_vx);
        float rvny = fmaf(rFy, INV_MASS_DT, r_vy);
        float rsp = sqrtf(fmaf(rvnx, rvnx, fmaf(rvny, rvny, EPSF)));
        float rsc = fminf(1.0f, PED_SPEEDF / rsp);
        rvnx *= rsc; rvny *= rsc;
        float rpx = fmaf(rvnx, DTF, r_px);          // new robot pose
        float rpy = fmaf(rvny, DTF, r_py);

        // --- this particle's update ---
        float px = state[i * 4 + 0], py = state[i * 4 + 1];
        float vx = state[i * 4 + 2], vy = state[i * 4 + 3];
        float2 gl = goals[i];
        float tgx = gl.x - px, tgy = gl.y - py;
        float distg = sqrtf(fmaf(tgx, tgx, fmaf(tgy, tgy, EPSF)));
        float des = (i == 0) ? 1.0f : PED_SPEEDF;
        float s = des / distg;
        float Fx = fx + 2.0f * (tgx * s - vx);
        float Fy = fy + 2.0f * (tgy * s - vy);
        float vnx = fmaf(Fx, INV_MASS_DT, vx);
        float vny = fmaf(Fy, INV_MASS_DT, vy);
        float sp = sqrtf(fmaf(vnx, vnx, fmaf(vny, vny, EPSF)));
        float scale = fminf(1.0f, PED_SPEEDF / sp);
        vnx *= scale; vny *= scale;
        float pnx = fmaf(vnx, DTF, px);
        float pny = fmaf(vny, DTF, py);
        out[i] = make_float4(pnx, pny, vnx, vny);

        // --- cost, fused ---
        float gx = goal[0], gy = goal[1];
        float ax = rip[0] - gx, ay = rip[1] - gy;
        float bx = rpx - gx, by = rpy - gy;
        float pg = sqrtf(fmaf(ax, ax, fmaf(ay, ay, EPSF)))
                 - sqrtf(fmaf(bx, bx, fmaf(by, by, EPSF)));
        float dx = pnx - rpx, dy = pny - rpy;
        float dr = sqrtf(fmaf(dx, dx, fmaf(dy, dy, EPSF)));
        float e = hw_exp2(dr * (-1.4426950408889634f / 1.5f)); // exp(-dr/1.5)
        newcost[i] = cost[i] + fmaf(5.0f, pg, 2.0f * e);
    }
}

extern "C" void kernel_launch(void* const* d_in, const int* in_sizes, int n_in,
                              void* d_out, int out_size, void* d_ws, size_t ws_size,
                              hipStream_t stream) {
    const float* state = (const float*)d_in[0];
    const float* cost  = (const float*)d_in[1];
    const float* goals = (const float*)d_in[2];
    const float* rip   = (const float*)d_in[3];
    const float* goal  = (const float*)d_in[4];
    float* out = (float*)d_out;

    step_kernel<<<N / G, BLK, 0, stream>>>(
        state, cost, (const float2*)goals, rip, goal,
        (float4*)out, out + 4 * N);
}